// Round 2
// baseline (25.062 us; speedup 1.0000x reference)
//
#include <hip/hip_runtime.h>

#define NBIN 50
#define DIM  64
#define TPB  256
#define KPT  4

__device__ __forceinline__ float u32_as_f32(unsigned int u) {
    union { unsigned int u; float f; } c; c.u = u; return c.f;
}
__device__ __forceinline__ unsigned int f32_bits(float f) {
    union { float f; unsigned int u; } c; c.f = f; return c.u;
}

// One block per batch row b. Per-b bin table folded with b1 + ego@W1[52:56],
// stored in LDS as bf16, packed [d8][bin][8 dims] so one ds_read_b128 gathers
// 8 feature dims. 8 gathers/output (was 16 f32) -> halves LDS pipe pressure.
// Uniform rows W1[50],W1[51],W2 read via wave-uniform const pointers (s_load).
__global__ __launch_bounds__(TPB, 4) void scorer_kernel(
    const float* __restrict__ goal,   // (B, K, 2)
    const float* __restrict__ ego,    // (B, 4)
    const float* __restrict__ W1,     // (56, 64) row-major
    const float* __restrict__ b1,     // (64)
    const float* __restrict__ W2,     // (64, 1)
    const float* __restrict__ b2,     // (1)
    float* __restrict__ out,          // (B, K)
    int K)
{
    __shared__ alignas(16) unsigned short comb[8 * NBIN * 8];  // bf16, 6.4 KB
    __shared__ float e_lds[DIM];

    const int b   = blockIdx.x;
    const int tid = threadIdx.x;

    // per-b ego/bias fold (uniform per block)
    const float4 eg = ((const float4*)ego)[b];
    if (tid < DIM) {
        e_lds[tid] = b1[tid]
                   + eg.x * W1[52 * DIM + tid]
                   + eg.y * W1[53 * DIM + tid]
                   + eg.z * W1[54 * DIM + tid]
                   + eg.w * W1[55 * DIM + tid];
    }
    __syncthreads();

    // build bf16 table: i = bin*64 + d (coalesced W1 reads)
    for (int i = tid; i < NBIN * DIM; i += TPB) {
        int bin = i >> 6;
        int d   = i & 63;
        float v = W1[i] + e_lds[d];
        unsigned int u = f32_bits(v);
        unsigned int r = (u + 0x7fffu + ((u >> 16) & 1u)) >> 16;   // RNE -> bf16
        comb[((d >> 3) * NBIN + bin) * 8 + (d & 7)] = (unsigned short)r;
    }
    __syncthreads();

    // each thread: 4 consecutive k -> 2x float4 goal loads, 1x float4 store
    const float4* gp4 = (const float4*)goal + (size_t)b * (K / 2);
    const float4  ga  = gp4[tid * 2];
    const float4  gb  = gp4[tid * 2 + 1];

    float2 p[KPT];
    int    idx[KPT];
    float  acc[KPT];
    p[0] = make_float2(ga.x, ga.y);
    p[1] = make_float2(ga.z, ga.w);
    p[2] = make_float2(gb.x, gb.y);
    p[3] = make_float2(gb.z, gb.w);

#pragma unroll
    for (int j = 0; j < KPT; ++j) {
        // exact IEEE f32 replication of jax: floor((sqrt(x*x+y*y)/50)*50)
        float r2 = __fadd_rn(__fmul_rn(p[j].x, p[j].x), __fmul_rn(p[j].y, p[j].y));
        float fv = floorf(__fmul_rn(__fdiv_rn(__fsqrt_rn(r2), 50.0f), 50.0f));
        int ix = (int)fv;
        idx[j] = ix < 0 ? 0 : (ix > NBIN - 1 ? NBIN - 1 : ix);
        acc[j] = 0.0f;
    }

    const float4* w50v  = (const float4*)(W1 + 50 * DIM);
    const float4* w51v  = (const float4*)(W1 + 51 * DIM);
    const float4* w2v   = (const float4*)W2;
    const uint4*  combv = (const uint4*)comb;
    const float   bias2 = b2[0];

#pragma unroll
    for (int d8 = 0; d8 < 8; ++d8) {
        const float4 a0 = w50v[d8 * 2];
        const float4 a1 = w50v[d8 * 2 + 1];
        const float4 q0 = w51v[d8 * 2];
        const float4 q1 = w51v[d8 * 2 + 1];
        const float4 c0 = w2v[d8 * 2];
        const float4 c1 = w2v[d8 * 2 + 1];
#pragma unroll
        for (int j = 0; j < KPT; ++j) {
            const uint4 g = combv[d8 * NBIN + idx[j]];   // ds_read_b128 gather, 8 dims
            const float x = p[j].x, y = p[j].y;
            float s = acc[j];
            // unpack bf16 (little-endian: even dim = low half)
            float h0 = u32_as_f32(g.x << 16), h1 = u32_as_f32(g.x & 0xffff0000u);
            float h2 = u32_as_f32(g.y << 16), h3 = u32_as_f32(g.y & 0xffff0000u);
            float h4 = u32_as_f32(g.z << 16), h5 = u32_as_f32(g.z & 0xffff0000u);
            float h6 = u32_as_f32(g.w << 16), h7 = u32_as_f32(g.w & 0xffff0000u);
            float t0 = fmaf(x, a0.x, fmaf(y, q0.x, h0));
            float t1 = fmaf(x, a0.y, fmaf(y, q0.y, h1));
            float t2 = fmaf(x, a0.z, fmaf(y, q0.z, h2));
            float t3 = fmaf(x, a0.w, fmaf(y, q0.w, h3));
            float t4 = fmaf(x, a1.x, fmaf(y, q1.x, h4));
            float t5 = fmaf(x, a1.y, fmaf(y, q1.y, h5));
            float t6 = fmaf(x, a1.z, fmaf(y, q1.z, h6));
            float t7 = fmaf(x, a1.w, fmaf(y, q1.w, h7));
            s = fmaf(c0.x, fmaxf(t0, 0.0f), s);
            s = fmaf(c0.y, fmaxf(t1, 0.0f), s);
            s = fmaf(c0.z, fmaxf(t2, 0.0f), s);
            s = fmaf(c0.w, fmaxf(t3, 0.0f), s);
            s = fmaf(c1.x, fmaxf(t4, 0.0f), s);
            s = fmaf(c1.y, fmaxf(t5, 0.0f), s);
            s = fmaf(c1.z, fmaxf(t6, 0.0f), s);
            s = fmaf(c1.w, fmaxf(t7, 0.0f), s);
            acc[j] = s;
        }
    }

    float4 res = make_float4(acc[0] + bias2, acc[1] + bias2,
                             acc[2] + bias2, acc[3] + bias2);
    ((float4*)out)[(size_t)b * (K / 4) + tid] = res;
}

extern "C" void kernel_launch(void* const* d_in, const int* in_sizes, int n_in,
                              void* d_out, int out_size, void* d_ws, size_t ws_size,
                              hipStream_t stream) {
    const float* goal = (const float*)d_in[0];
    const float* ego  = (const float*)d_in[1];
    const float* W1   = (const float*)d_in[2];
    const float* b1   = (const float*)d_in[3];
    const float* W2   = (const float*)d_in[4];
    const float* b2   = (const float*)d_in[5];
    float* out = (float*)d_out;

    int B = in_sizes[1] / 4;          // ego_state is (B, 4)
    int K = in_sizes[0] / (2 * B);    // goal_positions is (B, K, 2)

    scorer_kernel<<<dim3(B), dim3(TPB), 0, stream>>>(goal, ego, W1, b1, W2, b2, out, K);
}

// Round 3
// 23.706 us; speedup vs baseline: 1.0572x; 1.0572x over previous
//
#include <hip/hip_runtime.h>

#define NBIN 50
#define DIM  64
#define TPB  256
#define KPT  4
#define KMAX (TPB * KPT)   // 1024 = K

// One block per batch row b.
// 1) compute bin per k (exact IEEE f32 replication of the jax formula)
// 2) counting-sort the block's 1024 k's by bin (LDS atomics + wave-0 scan)
// 3) gather loop over sorted order: lanes in a wave-round share ~4-6 bins,
//    so the [d4][bin] float4 table gathers are broadcast-merged (conflict-free)
// 4) scatter scores to LDS by original k, coalesced float4 store.
__global__ __launch_bounds__(TPB, 5) void scorer_kernel(
    const float* __restrict__ goal,   // (B, K, 2)
    const float* __restrict__ ego,    // (B, 4)
    const float* __restrict__ W1,     // (56, 64) row-major
    const float* __restrict__ b1,     // (64)
    const float* __restrict__ W2,     // (64, 1)
    const float* __restrict__ b2,     // (1)
    float* __restrict__ out)          // (B, K)
{
    __shared__ float4 comb[16 * NBIN];          // 12.8 KB  [d4][bin]
    __shared__ float  e_lds[DIM];
    __shared__ float2 sxy[KMAX];                // 8 KB sorted (x,y)
    __shared__ unsigned short smeta[KMAX];      // 2 KB  k | bin<<10
    __shared__ int    cnt[NBIN];
    __shared__ int    pfx[NBIN];
    __shared__ float  sout[KMAX];               // 4 KB scores by original k

    const int b   = blockIdx.x;
    const int tid = threadIdx.x;

    // ---- phase 0: loads + init ----
    const float4* gp4 = (const float4*)goal + (size_t)b * (KMAX / 2);
    const float4  ga  = gp4[tid * 2];
    const float4  gb  = gp4[tid * 2 + 1];
    const float4  eg  = ((const float4*)ego)[b];

    if (tid < DIM) {
        e_lds[tid] = b1[tid]
                   + eg.x * W1[52 * DIM + tid]
                   + eg.y * W1[53 * DIM + tid]
                   + eg.z * W1[54 * DIM + tid]
                   + eg.w * W1[55 * DIM + tid];
    }
    if (tid < NBIN) cnt[tid] = 0;
    __syncthreads();   // A: cnt zeroed, e_lds ready

    // ---- phase 1: bins + within-bin rank; comb table build ----
    float2 p[KPT];
    p[0] = make_float2(ga.x, ga.y);
    p[1] = make_float2(ga.z, ga.w);
    p[2] = make_float2(gb.x, gb.y);
    p[3] = make_float2(gb.z, gb.w);

    int bin[KPT], rnk[KPT];
#pragma unroll
    for (int j = 0; j < KPT; ++j) {
        // exact IEEE f32: floor((sqrt(x*x+y*y)/50)*50), clipped
        float r2 = __fadd_rn(__fmul_rn(p[j].x, p[j].x), __fmul_rn(p[j].y, p[j].y));
        float fv = floorf(__fmul_rn(__fdiv_rn(__fsqrt_rn(r2), 50.0f), 50.0f));
        int ix = (int)fv;
        bin[j] = ix < 0 ? 0 : (ix > NBIN - 1 ? NBIN - 1 : ix);
        rnk[j] = atomicAdd(&cnt[bin[j]], 1);
    }
    for (int i = tid; i < NBIN * DIM; i += TPB) {
        int bn = i >> 6;
        int d  = i & 63;
        ((float*)comb)[(((d >> 2) * NBIN) + bn) * 4 + (d & 3)] = W1[i] + e_lds[d];
    }
    __syncthreads();   // B: cnt final, comb final

    // ---- phase 2: exclusive prefix scan of cnt (wave 0) ----
    if (tid < 64) {
        int v = (tid < NBIN) ? cnt[tid] : 0;
        int incl = v;
#pragma unroll
        for (int d = 1; d < 64; d <<= 1) {
            int up = __shfl_up(incl, d, 64);
            if (tid >= d) incl += up;
        }
        if (tid < NBIN) pfx[tid] = incl - v;
    }
    __syncthreads();   // C: pfx ready

    // ---- phase 3: scatter into sorted order ----
#pragma unroll
    for (int j = 0; j < KPT; ++j) {
        int pos = pfx[bin[j]] + rnk[j];
        sxy[pos]   = p[j];
        smeta[pos] = (unsigned short)((tid * KPT + j) | (bin[j] << 10));
    }
    __syncthreads();   // D: sorted arrays ready

    // ---- phase 4: main loop over sorted positions ----
    const float4* w50v = (const float4*)(W1 + 50 * DIM);
    const float4* w51v = (const float4*)(W1 + 51 * DIM);
    const float4* w2v  = (const float4*)W2;
    const float  bias2 = b2[0];

    float2 q[KPT];
    int    sb[KPT], sk[KPT];
    float  acc[KPT];
#pragma unroll
    for (int j = 0; j < KPT; ++j) {
        int s = j * TPB + tid;          // consecutive lanes -> consecutive sorted pos
        q[j]  = sxy[s];
        int m = smeta[s];
        sk[j] = m & (KMAX - 1);
        sb[j] = m >> 10;
        acc[j] = 0.0f;
    }

#pragma unroll
    for (int d4 = 0; d4 < 16; ++d4) {
        const float4 a = w50v[d4];   // uniform -> s_load
        const float4 u = w51v[d4];   // uniform -> s_load
        const float4 c = w2v[d4];    // uniform -> s_load
#pragma unroll
        for (int j = 0; j < KPT; ++j) {
            const float4 g = comb[d4 * NBIN + sb[j]];  // mostly-broadcast gather
            const float x = q[j].x, y = q[j].y;
            float t0 = fmaf(x, a.x, fmaf(y, u.x, g.x));
            float t1 = fmaf(x, a.y, fmaf(y, u.y, g.y));
            float t2 = fmaf(x, a.z, fmaf(y, u.z, g.z));
            float t3 = fmaf(x, a.w, fmaf(y, u.w, g.w));
            acc[j] = fmaf(c.x, fmaxf(t0, 0.0f), acc[j]);
            acc[j] = fmaf(c.y, fmaxf(t1, 0.0f), acc[j]);
            acc[j] = fmaf(c.z, fmaxf(t2, 0.0f), acc[j]);
            acc[j] = fmaf(c.w, fmaxf(t3, 0.0f), acc[j]);
        }
    }

    // ---- phase 5: scatter scores by original k, coalesced store ----
#pragma unroll
    for (int j = 0; j < KPT; ++j) sout[sk[j]] = acc[j] + bias2;
    __syncthreads();   // E

    float4 res = make_float4(sout[tid * 4], sout[tid * 4 + 1],
                             sout[tid * 4 + 2], sout[tid * 4 + 3]);
    ((float4*)out)[(size_t)b * (KMAX / 4) + tid] = res;
}

extern "C" void kernel_launch(void* const* d_in, const int* in_sizes, int n_in,
                              void* d_out, int out_size, void* d_ws, size_t ws_size,
                              hipStream_t stream) {
    const float* goal = (const float*)d_in[0];
    const float* ego  = (const float*)d_in[1];
    const float* W1   = (const float*)d_in[2];
    const float* b1   = (const float*)d_in[3];
    const float* W2   = (const float*)d_in[4];
    const float* b2   = (const float*)d_in[5];
    float* out = (float*)d_out;

    int B = in_sizes[1] / 4;          // ego_state is (B, 4); K fixed at 1024
    scorer_kernel<<<dim3(B), dim3(TPB), 0, stream>>>(goal, ego, W1, b1, W2, b2, out);
}

// Round 4
// 23.583 us; speedup vs baseline: 1.0627x; 1.0052x over previous
//
#include <hip/hip_runtime.h>

#define NBIN 50
#define DIM  64
#define TPB  512   // one block per b; 2 outputs per thread

typedef float f32x2 __attribute__((ext_vector_type(2)));

// t = v * s + c   (s is wave-uniform -> SGPR pair; one scalar operand per VOP3P is legal)
__device__ __forceinline__ f32x2 pk_fma_vs(f32x2 v, f32x2 s, f32x2 c) {
    f32x2 r;
    asm("v_pk_fma_f32 %0, %1, %2, %3" : "=v"(r) : "v"(v), "s"(s), "v"(c));
    return r;
}
// acc = s * t + acc
__device__ __forceinline__ f32x2 pk_fma_acc(f32x2 s, f32x2 t, f32x2 acc) {
    asm("v_pk_fma_f32 %0, %1, %2, %0" : "+v"(acc) : "s"(s), "v"(t));
    return acc;
}

__global__ __launch_bounds__(TPB, 8) void scorer_kernel(
    const float* __restrict__ goal,   // (B, K, 2)
    const float* __restrict__ ego,    // (B, 4)
    const float* __restrict__ W1,     // (56, 64) row-major
    const float* __restrict__ b1,     // (64)
    const float* __restrict__ W2,     // (64, 1)
    const float* __restrict__ b2,     // (1)
    float* __restrict__ out)          // (B, K), K = 1024
{
    __shared__ float4 comb[16 * NBIN];   // [d4][bin] float4, 12.8 KB

    const int b   = blockIdx.x;
    const int tid = threadIdx.x;

    // 2 consecutive k per thread: one float4 = (x0,y0,x1,y1)
    const float4 g4 = ((const float4*)goal)[(size_t)b * (1024 / 2) + tid];
    const float4 eg = ((const float4*)ego)[b];

    // this thread always writes table column d = tid & 63 -> fold ego once, no LDS stage
    const int   d  = tid & 63;
    const float ev = b1[d]
                   + eg.x * W1[52 * DIM + d]
                   + eg.y * W1[53 * DIM + d]
                   + eg.z * W1[54 * DIM + d]
                   + eg.w * W1[55 * DIM + d];

    // bins: exact IEEE f32 replication of floor((sqrt(x*x+y*y)/50)*50), clipped
    const float2 p0 = make_float2(g4.x, g4.y);
    const float2 p1 = make_float2(g4.z, g4.w);
    int idx0, idx1;
    {
        float r2 = __fadd_rn(__fmul_rn(p0.x, p0.x), __fmul_rn(p0.y, p0.y));
        float fv = floorf(__fmul_rn(__fdiv_rn(__fsqrt_rn(r2), 50.0f), 50.0f));
        int ix = (int)fv;
        idx0 = ix < 0 ? 0 : (ix > NBIN - 1 ? NBIN - 1 : ix);
    }
    {
        float r2 = __fadd_rn(__fmul_rn(p1.x, p1.x), __fmul_rn(p1.y, p1.y));
        float fv = floorf(__fmul_rn(__fdiv_rn(__fsqrt_rn(r2), 50.0f), 50.0f));
        int ix = (int)fv;
        idx1 = ix < 0 ? 0 : (ix > NBIN - 1 ? NBIN - 1 : ix);
    }

    // table build: i = bin*64 + d (coalesced W1 reads); d fixed per thread
    for (int i = tid; i < NBIN * DIM; i += TPB) {
        int bn = i >> 6;
        ((float*)comb)[((d >> 2) * NBIN + bn) * 4 + (d & 3)] = W1[i] + ev;
    }
    __syncthreads();

    const f32x2* w50v = (const f32x2*)(W1 + 50 * DIM);
    const f32x2* w51v = (const f32x2*)(W1 + 51 * DIM);
    const f32x2* w2v  = (const f32x2*)W2;
    const float  bias2 = b2[0];

    const f32x2 xx0 = {p0.x, p0.x}, yy0 = {p0.y, p0.y};
    const f32x2 xx1 = {p1.x, p1.x}, yy1 = {p1.y, p1.y};
    f32x2 a0l = {0.f, 0.f}, a0h = {0.f, 0.f};   // output 0 accumulators
    f32x2 a1l = {0.f, 0.f}, a1h = {0.f, 0.f};   // output 1 accumulators

#pragma unroll
    for (int d4 = 0; d4 < 16; ++d4) {
        const f32x2 wa0 = w50v[d4 * 2], wa1 = w50v[d4 * 2 + 1];  // uniform -> s_load
        const f32x2 wu0 = w51v[d4 * 2], wu1 = w51v[d4 * 2 + 1];
        const f32x2 wc0 = w2v[d4 * 2],  wc1 = w2v[d4 * 2 + 1];
        const float4 ga = comb[d4 * NBIN + idx0];  // ds_read_b128
        const float4 gb = comb[d4 * NBIN + idx1];  // ds_read_b128

        f32x2 t;
        // output 0, dims [4*d4, 4*d4+1]
        t = pk_fma_vs(yy0, wu0, (f32x2){ga.x, ga.y});
        t = pk_fma_vs(xx0, wa0, t);
        t.x = fmaxf(t.x, 0.0f); t.y = fmaxf(t.y, 0.0f);
        a0l = pk_fma_acc(wc0, t, a0l);
        // output 0, dims [4*d4+2, 4*d4+3]
        t = pk_fma_vs(yy0, wu1, (f32x2){ga.z, ga.w});
        t = pk_fma_vs(xx0, wa1, t);
        t.x = fmaxf(t.x, 0.0f); t.y = fmaxf(t.y, 0.0f);
        a0h = pk_fma_acc(wc1, t, a0h);
        // output 1, dims [4*d4, 4*d4+1]
        t = pk_fma_vs(yy1, wu0, (f32x2){gb.x, gb.y});
        t = pk_fma_vs(xx1, wa0, t);
        t.x = fmaxf(t.x, 0.0f); t.y = fmaxf(t.y, 0.0f);
        a1l = pk_fma_acc(wc0, t, a1l);
        // output 1, dims [4*d4+2, 4*d4+3]
        t = pk_fma_vs(yy1, wu1, (f32x2){gb.z, gb.w});
        t = pk_fma_vs(xx1, wa1, t);
        t.x = fmaxf(t.x, 0.0f); t.y = fmaxf(t.y, 0.0f);
        a1h = pk_fma_acc(wc1, t, a1h);
    }

    const float s0 = a0l.x + a0l.y + a0h.x + a0h.y + bias2;
    const float s1 = a1l.x + a1l.y + a1h.x + a1h.y + bias2;
    ((float2*)out)[(size_t)b * TPB + tid] = make_float2(s0, s1);
}

extern "C" void kernel_launch(void* const* d_in, const int* in_sizes, int n_in,
                              void* d_out, int out_size, void* d_ws, size_t ws_size,
                              hipStream_t stream) {
    const float* goal = (const float*)d_in[0];
    const float* ego  = (const float*)d_in[1];
    const float* W1   = (const float*)d_in[2];
    const float* b1   = (const float*)d_in[3];
    const float* W2   = (const float*)d_in[4];
    const float* b2   = (const float*)d_in[5];
    float* out = (float*)d_out;

    int B = in_sizes[1] / 4;          // ego_state is (B, 4); K fixed at 1024
    scorer_kernel<<<dim3(B), dim3(TPB), 0, stream>>>(goal, ego, W1, b1, W2, b2, out);
}